// Round 6
// baseline (235.404 us; speedup 1.0000x reference)
//
#include <hip/hip_runtime.h>

#define C 128
#define NEG_SLOPE 0.2f
#define SM_EPS 1e-16f
#define BKT_SHIFT 6            // 64 nodes per bucket
#define BKT_MASK 63
#define NB_MAX 1024
#define BIN_CHUNK 4096
#define WP 136                 // gemm LDS pitch (u16 units)

typedef unsigned int uint32;
typedef __attribute__((ext_vector_type(8))) short bf16x8;
typedef __attribute__((ext_vector_type(4))) float f32x4;

// ---- bf16 helpers (RNE) ----
static __device__ __forceinline__ unsigned short f2bf(float f) {
    uint32 u = __float_as_uint(f);
    uint32 r = 0x7FFFu + ((u >> 16) & 1u);
    return (unsigned short)((u + r) >> 16);
}
static __device__ __forceinline__ uint32 f2bf2(float lo, float hi) {
    return (uint32)f2bf(lo) | ((uint32)f2bf(hi) << 16);
}

// ---- MFMA bf16 GEMM (h = x @ W) + alpha_s/alpha_d + bf16 h store ----
__global__ __launch_bounds__(256) void gemm_mfma_kernel(
    const float* __restrict__ x, const float* __restrict__ W,
    const float* __restrict__ a_src, const float* __restrict__ a_dst,
    unsigned short* __restrict__ hb, float* __restrict__ as_out,
    float* __restrict__ ad_out, int N)
{
    __shared__ __align__(16) unsigned short Wl[128 * WP];  // W^T bf16: [n][k]
    __shared__ __align__(16) unsigned short Xl[64 * WP];   // x bf16:  [r][k]

    const int tid  = threadIdx.x;
    const int lane = tid & 63;
    const int w    = tid >> 6;
    const int row0 = blockIdx.x * 64;

    for (int i = tid; i < 64 * 128; i += 256) {
        int n = i & 127, kp = i >> 7;
        float w0 = W[(2 * kp) * C + n];
        float w1 = W[(2 * kp + 1) * C + n];
        *(uint32*)&Wl[n * WP + 2 * kp] = f2bf2(w0, w1);
    }
    for (int i = tid; i < 64 * 64; i += 256) {
        int r = i >> 6, kp = i & 63;
        int row = row0 + r;
        float2 xv = (row < N) ? *(const float2*)&x[(size_t)row * C + 2 * kp]
                              : make_float2(0.f, 0.f);
        *(uint32*)&Xl[r * WP + 2 * kp] = f2bf2(xv.x, xv.y);
    }
    __syncthreads();

    const int m16 = lane & 15;
    const int q   = lane >> 4;

    f32x4 acc[8];
    const f32x4 zz = {0.f, 0.f, 0.f, 0.f};
    #pragma unroll
    for (int t = 0; t < 8; ++t) acc[t] = zz;

    #pragma unroll
    for (int kk = 0; kk < 4; ++kk) {
        const int k0 = kk * 32 + q * 8;
        bf16x8 a = *(const bf16x8*)&Xl[(w * 16 + m16) * WP + k0];
        #pragma unroll
        for (int t = 0; t < 8; ++t) {
            bf16x8 b = *(const bf16x8*)&Wl[(t * 16 + m16) * WP + k0];
            acc[t] = __builtin_amdgcn_mfma_f32_16x16x32_bf16(a, b, acc[t], 0, 0, 0);
        }
    }

    float ps[4] = {0.f, 0.f, 0.f, 0.f}, pd[4] = {0.f, 0.f, 0.f, 0.f};
    #pragma unroll
    for (int t = 0; t < 8; ++t) {
        float av = a_src[t * 16 + m16];
        float dv = a_dst[t * 16 + m16];
        #pragma unroll
        for (int r = 0; r < 4; ++r) {
            ps[r] += acc[t][r] * av;
            pd[r] += acc[t][r] * dv;
        }
    }
    #pragma unroll
    for (int r = 0; r < 4; ++r) {
        #pragma unroll
        for (int off = 1; off < 16; off <<= 1) {
            ps[r] += __shfl_xor(ps[r], off, 64);
            pd[r] += __shfl_xor(pd[r], off, 64);
        }
    }
    if (m16 == 0) {
        #pragma unroll
        for (int r = 0; r < 4; ++r) {
            int row = row0 + w * 16 + q * 4 + r;
            if (row < N) { as_out[row] = ps[r]; ad_out[row] = pd[r]; }
        }
    }

    unsigned short* slice = &Xl[w * 16 * WP];
    #pragma unroll
    for (int t = 0; t < 8; ++t)
        #pragma unroll
        for (int r = 0; r < 4; ++r)
            slice[(q * 4 + r) * WP + t * 16 + m16] = f2bf(acc[t][r]);
    __syncthreads();
    #pragma unroll
    for (int it = 0; it < 4; ++it) {
        int r = it * 4 + q;
        int row = row0 + w * 16 + r;
        if (row < N) {
            bf16x8 v = *(const bf16x8*)&slice[r * WP + m16 * 8];
            *(bf16x8*)&hb[(size_t)row * C + m16 * 8] = v;
        }
    }
}

// ---- zero small int buffer ----
__global__ void zero_kernel(int* __restrict__ p, int n) {
    int i = blockIdx.x * blockDim.x + threadIdx.x;
    if (i < n) p[i] = 0;
}

// ---- binning step 1: bucket histogram ----
__global__ __launch_bounds__(256) void hist_kernel(
    const int* __restrict__ dst, int* __restrict__ bucket_cnt,
    int E, int total, int NB)
{
    __shared__ int hist[NB_MAX];
    const int tid = threadIdx.x;
    for (int i = tid; i < NB; i += 256) hist[i] = 0;
    __syncthreads();
    for (int i = blockIdx.x * 256 + tid; i < total; i += gridDim.x * 256) {
        int d = (i < E) ? dst[i] : (i - E);
        atomicAdd(&hist[d >> BKT_SHIFT], 1);
    }
    __syncthreads();
    for (int i = tid; i < NB; i += 256)
        if (hist[i]) atomicAdd(&bucket_cnt[i], hist[i]);
}

// ---- binning step 2: exclusive scan of bucket counts (multi-chunk, 1 block) ----
__global__ __launch_bounds__(256) void scan_off_kernel(
    const int* __restrict__ bucket_cnt, int* __restrict__ bucket_off,
    int* __restrict__ bucket_cursor, int* __restrict__ row_start,
    int NB, int N, int total)
{
    __shared__ int wave_tot[4];
    __shared__ int s_running;
    const int tid = threadIdx.x, lane = tid & 63, wid = tid >> 6;
    if (tid == 0) s_running = 0;
    __syncthreads();

    for (int base = 0; base < NB; base += 256) {
        int i = base + tid;
        int v = (i < NB) ? bucket_cnt[i] : 0;
        int x = v;
        #pragma unroll
        for (int off = 1; off < 64; off <<= 1) {
            int t = __shfl_up(x, off, 64);
            if (lane >= off) x += t;
        }
        if (lane == 63) wave_tot[wid] = x;
        __syncthreads();
        int wbase = 0;
        #pragma unroll
        for (int w = 0; w < 4; ++w) wbase += (w < wid) ? wave_tot[w] : 0;
        int excl = s_running + wbase + x - v;
        if (i < NB) { bucket_off[i] = excl; bucket_cursor[i] = excl; }
        __syncthreads();
        if (tid == 0) s_running += wave_tot[0] + wave_tot[1] + wave_tot[2] + wave_tot[3];
        __syncthreads();
    }
    if (tid == 0) { bucket_off[NB] = total; row_start[N] = total; }
}

// ---- binning step 3: scatter into bucket-contiguous packed runs ----
// packed = (src << 6) | (dst & 63)
__global__ __launch_bounds__(256) void bin_kernel(
    const int* __restrict__ src, const int* __restrict__ dst,
    int* __restrict__ bucket_cursor, uint32* __restrict__ packed,
    int E, int total, int NB)
{
    __shared__ int hist[NB_MAX];
    __shared__ int base[NB_MAX];
    const int tid = threadIdx.x;
    const int start = blockIdx.x * BIN_CHUNK;
    const int end = min(start + BIN_CHUNK, total);

    for (int i = tid; i < NB; i += 256) hist[i] = 0;
    __syncthreads();
    for (int i = start + tid; i < end; i += 256) {
        int d = (i < E) ? dst[i] : (i - E);
        atomicAdd(&hist[d >> BKT_SHIFT], 1);
    }
    __syncthreads();
    for (int i = tid; i < NB; i += 256) {
        int c = hist[i];
        base[i] = c ? atomicAdd(&bucket_cursor[i], c) : 0;
        hist[i] = 0;
    }
    __syncthreads();
    for (int i = start + tid; i < end; i += 256) {
        int s = (i < E) ? src[i] : (i - E);
        int d = (i < E) ? dst[i] : (i - E);
        int b = d >> BKT_SHIFT;
        int pos = base[b] + atomicAdd(&hist[b], 1);
        packed[pos] = ((uint32)s << BKT_SHIFT) | (uint32)(d & BKT_MASK);
    }
}

// ---- binning step 4: per-bucket fine sort + fused e computation ----
// csr entry = uint2{ src, float_bits(leaky(as[src] + ad[dst])) }
__global__ __launch_bounds__(256) void build_kernel(
    const uint32* __restrict__ packed, const int* __restrict__ bucket_off,
    const float* __restrict__ as, const float* __restrict__ ad,
    int* __restrict__ row_start, uint2* __restrict__ csr, int N)
{
    __shared__ int cnt[64];
    __shared__ int cur[64];
    __shared__ float adl[64];
    const int tid = threadIdx.x;
    const int b = blockIdx.x;
    const int off = bucket_off[b];
    const int end = bucket_off[b + 1];

    if (tid < 64) {
        cnt[tid] = 0;
        int g = (b << BKT_SHIFT) + tid;
        adl[tid] = (g < N) ? ad[g] : 0.f;
    }
    __syncthreads();
    for (int j = off + tid; j < end; j += 256)
        atomicAdd(&cnt[packed[j] & BKT_MASK], 1);
    __syncthreads();

    if (tid < 64) {       // wave 0: 64-entry exclusive scan
        int v = cnt[tid], x = v;
        #pragma unroll
        for (int o = 1; o < 64; o <<= 1) {
            int t = __shfl_up(x, o, 64);
            if (tid >= o) x += t;
        }
        int excl = x - v;
        int g = (b << BKT_SHIFT) + tid;
        if (g < N) row_start[g] = off + excl;
        cur[tid] = excl;
    }
    __syncthreads();

    for (int j = off + tid; j < end; j += 256) {
        uint32 p = packed[j];
        int l = (int)(p & BKT_MASK);
        int s = (int)(p >> BKT_SHIFT);
        float e = as[s] + adl[l];
        e = (e > 0.f) ? e : NEG_SLOPE * e;
        int pos = atomicAdd(&cur[l], 1);
        csr[off + pos] = make_uint2((uint32)s, __float_as_uint(e));
    }
}

// ---- fused softmax + gather-aggregate + bias + relu (register-resident) ----
// one wave per dst; edge t lives in lane t's registers; no LDS.
__global__ __launch_bounds__(256) void gather_kernel(
    const uint2* __restrict__ csr, const int* __restrict__ row_start,
    const unsigned short* __restrict__ hb, const float* __restrict__ bias,
    float* __restrict__ out, int N)
{
    const int w    = threadIdx.x >> 6;
    const int lane = threadIdx.x & 63;
    const int d = blockIdx.x * 4 + w;
    if (d >= N) return;                     // no barriers below: safe

    const int beg = row_start[d];
    const int deg = row_start[d + 1] - beg;
    const int c2 = lane << 1;
    float a0 = 0.f, a1 = 0.f;

    if (deg <= 64) {
        uint2 ent = (lane < deg) ? csr[beg + lane] : make_uint2(0u, 0xFF800000u);
        float e = __uint_as_float(ent.y);
        float m = e;
        #pragma unroll
        for (int off = 32; off > 0; off >>= 1) m = fmaxf(m, __shfl_xor(m, off, 64));
        float p = (lane < deg) ? __expf(e - m) : 0.f;
        float ssum = p;
        #pragma unroll
        for (int off = 32; off > 0; off >>= 1) ssum += __shfl_xor(ssum, off, 64);
        float wgt = p * (1.f / (ssum + SM_EPS));

        int t = 0;
        for (; t + 4 <= deg; t += 4) {
            int s0 = __shfl((int)ent.x, t, 64),     s1 = __shfl((int)ent.x, t + 1, 64);
            int s2 = __shfl((int)ent.x, t + 2, 64), s3 = __shfl((int)ent.x, t + 3, 64);
            float w0 = __shfl(wgt, t, 64),     w1 = __shfl(wgt, t + 1, 64);
            float w2 = __shfl(wgt, t + 2, 64), w3 = __shfl(wgt, t + 3, 64);
            uint32 u0 = *(const uint32*)&hb[(size_t)s0 * C + c2];
            uint32 u1 = *(const uint32*)&hb[(size_t)s1 * C + c2];
            uint32 u2 = *(const uint32*)&hb[(size_t)s2 * C + c2];
            uint32 u3 = *(const uint32*)&hb[(size_t)s3 * C + c2];
            a0 += __uint_as_float(u0 << 16) * w0 + __uint_as_float(u1 << 16) * w1
                + __uint_as_float(u2 << 16) * w2 + __uint_as_float(u3 << 16) * w3;
            a1 += __uint_as_float(u0 & 0xffff0000u) * w0 + __uint_as_float(u1 & 0xffff0000u) * w1
                + __uint_as_float(u2 & 0xffff0000u) * w2 + __uint_as_float(u3 & 0xffff0000u) * w3;
        }
        for (; t < deg; ++t) {
            int s0 = __shfl((int)ent.x, t, 64);
            float w0 = __shfl(wgt, t, 64);
            uint32 u0 = *(const uint32*)&hb[(size_t)s0 * C + c2];
            a0 += __uint_as_float(u0 << 16) * w0;
            a1 += __uint_as_float(u0 & 0xffff0000u) * w0;
        }
    } else if (deg <= 128) {
        uint2 ea = (lane < deg) ? csr[beg + lane] : make_uint2(0u, 0xFF800000u);
        uint2 eb = (64 + lane < deg) ? csr[beg + 64 + lane] : make_uint2(0u, 0xFF800000u);
        float e0 = __uint_as_float(ea.y), e1 = __uint_as_float(eb.y);
        float m = fmaxf(e0, e1);
        #pragma unroll
        for (int off = 32; off > 0; off >>= 1) m = fmaxf(m, __shfl_xor(m, off, 64));
        float p0 = (lane < deg) ? __expf(e0 - m) : 0.f;
        float p1 = (64 + lane < deg) ? __expf(e1 - m) : 0.f;
        float ssum = p0 + p1;
        #pragma unroll
        for (int off = 32; off > 0; off >>= 1) ssum += __shfl_xor(ssum, off, 64);
        float inv = 1.f / (ssum + SM_EPS);
        float wa = p0 * inv, wb = p1 * inv;
        for (int t = 0; t < deg; ++t) {
            int s0; float w0;
            if (t < 64) { s0 = __shfl((int)ea.x, t, 64); w0 = __shfl(wa, t, 64); }
            else        { s0 = __shfl((int)eb.x, t - 64, 64); w0 = __shfl(wb, t - 64, 64); }
            uint32 u0 = *(const uint32*)&hb[(size_t)s0 * C + c2];
            a0 += __uint_as_float(u0 << 16) * w0;
            a1 += __uint_as_float(u0 & 0xffff0000u) * w0;
        }
    } else {
        // chunked fallback (not expected at this size)
        float m = -INFINITY;
        for (int t = lane; t < deg; t += 64)
            m = fmaxf(m, __uint_as_float(csr[beg + t].y));
        #pragma unroll
        for (int off = 32; off > 0; off >>= 1) m = fmaxf(m, __shfl_xor(m, off, 64));
        float ssum = 0.f;
        for (int t = lane; t < deg; t += 64)
            ssum += __expf(__uint_as_float(csr[beg + t].y) - m);
        #pragma unroll
        for (int off = 32; off > 0; off >>= 1) ssum += __shfl_xor(ssum, off, 64);
        float inv = 1.f / (ssum + SM_EPS);
        for (int t0 = 0; t0 < deg; t0 += 64) {
            int nc = min(64, deg - t0);
            uint2 ent = (lane < nc) ? csr[beg + t0 + lane] : make_uint2(0u, 0xFF800000u);
            float wl = (lane < nc) ? __expf(__uint_as_float(ent.y) - m) * inv : 0.f;
            for (int t = 0; t < nc; ++t) {
                int s0 = __shfl((int)ent.x, t, 64);
                float w0 = __shfl(wl, t, 64);
                uint32 u0 = *(const uint32*)&hb[(size_t)s0 * C + c2];
                a0 += __uint_as_float(u0 << 16) * w0;
                a1 += __uint_as_float(u0 & 0xffff0000u) * w0;
            }
        }
    }

    float2 b2 = *(const float2*)&bias[c2];
    a0 = fmaxf(a0 + b2.x, 0.f);
    a1 = fmaxf(a1 + b2.y, 0.f);
    *(float2*)&out[(size_t)d * C + c2] = make_float2(a0, a1);
}

extern "C" void kernel_launch(void* const* d_in, const int* in_sizes, int n_in,
                              void* d_out, int out_size, void* d_ws, size_t ws_size,
                              hipStream_t stream) {
    const float* x     = (const float*)d_in[0];
    const float* W     = (const float*)d_in[1];
    const float* a_src = (const float*)d_in[2];
    const float* a_dst = (const float*)d_in[3];
    const float* bias  = (const float*)d_in[4];
    const int*   edge  = (const int*)d_in[5];

    const int N = in_sizes[0] / C;
    const int E = in_sizes[5] / 2;
    const int total = E + N;
    const int* src = edge;
    const int* dst = edge + E;
    float* out = (float*)d_out;

    const int NB = (N + BKT_MASK) >> BKT_SHIFT;   // 782 buckets

    // workspace (4B units):
    // hb[N*C/2] | as[N] | ad[N] | row_start[N+1] | packed[total] | csr[2*total]
    // | bucket_cnt[NB] | bucket_off[NB+1] | bucket_cursor[NB]
    float* ws = (float*)d_ws;
    unsigned short* hb = (unsigned short*)ws;
    float* as = (float*)(hb + (size_t)N * C);
    float* ad = as + N;
    int* row_start     = (int*)(ad + N);
    uint32* packed     = (uint32*)(row_start + (N + 1));
    uint2* csr         = (uint2*)(packed + total);
    int* bucket_cnt    = (int*)(csr + total);
    int* bucket_off    = bucket_cnt + NB;
    int* bucket_cursor = bucket_off + (NB + 1);

    zero_kernel<<<(NB + 255) / 256, 256, 0, stream>>>(bucket_cnt, NB);
    gemm_mfma_kernel<<<(N + 63) / 64, 256, 0, stream>>>(x, W, a_src, a_dst, hb, as, ad, N);
    hist_kernel<<<256, 256, 0, stream>>>(dst, bucket_cnt, E, total, NB);
    scan_off_kernel<<<1, 256, 0, stream>>>(bucket_cnt, bucket_off, bucket_cursor,
                                           row_start, NB, N, total);
    bin_kernel<<<(total + BIN_CHUNK - 1) / BIN_CHUNK, 256, 0, stream>>>(
        src, dst, bucket_cursor, packed, E, total, NB);
    build_kernel<<<NB, 256, 0, stream>>>(packed, bucket_off, as, ad, row_start, csr, N);
    gather_kernel<<<(N + 3) / 4, 256, 0, stream>>>(csr, row_start, hb, bias, out, N);
}